// Round 2
// baseline (154.882 us; speedup 1.0000x reference)
//
#include <hip/hip_runtime.h>
#include <hip/hip_bf16.h>

// Problem constants (from reference)
#define BATCH 512
#define NKER  256
#define LEN   1000      // embedding input length
#define EDIM  3
#define OUTN  128
#define NROWS (BATCH * NKER)      // 131072
#define NF4   (LEN / 4)           // 250 float4 per row
#define FC_IN (EDIM * NKER)       // 768
#define S2_ROWS 8                 // batch rows per stage-2 block

// ---------------- Stage 1: y[b,k,e] = sum_l x[b,k,l] * W_emb[e,l] ----------
// One wave per (b,k) row. W_emb held in registers (per-lane positions are
// row-invariant). All 4 x float4 loads issued up front; tail predicated.
__global__ __launch_bounds__(256) void stage1_emb(const float* __restrict__ x,
                                                  const float* __restrict__ W_emb,
                                                  float* __restrict__ y) {
    const int wave = threadIdx.x >> 6;
    const int lane = threadIdx.x & 63;

    // Per-lane W fragments: f = lane + 64*j, j = 0..3 (j=3 only if lane < 58)
    const float4* __restrict__ w0p = reinterpret_cast<const float4*>(W_emb);
    const float4* __restrict__ w1p = reinterpret_cast<const float4*>(W_emb + LEN);
    const float4* __restrict__ w2p = reinterpret_cast<const float4*>(W_emb + 2 * LEN);
    const bool tail = (lane < NF4 - 192);   // lane < 58
    float4 w0[4], w1[4], w2[4];
    #pragma unroll
    for (int j = 0; j < 3; ++j) {
        w0[j] = w0p[lane + 64 * j];
        w1[j] = w1p[lane + 64 * j];
        w2[j] = w2p[lane + 64 * j];
    }
    const float4 z4 = make_float4(0.f, 0.f, 0.f, 0.f);
    w0[3] = tail ? w0p[lane + 192] : z4;
    w1[3] = tail ? w1p[lane + 192] : z4;
    w2[3] = tail ? w2p[lane + 192] : z4;

    const int waves_total = gridDim.x * 4;
    for (int row = blockIdx.x * 4 + wave; row < NROWS; row += waves_total) {
        const float4* __restrict__ xr =
            reinterpret_cast<const float4*>(x + (size_t)row * LEN);
        // Issue all 4 loads before any use (max loads in flight)
        float4 xv0 = xr[lane];
        float4 xv1 = xr[lane + 64];
        float4 xv2 = xr[lane + 128];
        float4 xv3 = tail ? xr[lane + 192] : z4;

        float s0 = 0.f, s1 = 0.f, s2 = 0.f;
        #pragma unroll
        for (int j = 0; j < 4; ++j) {
            const float4 xv = (j == 0) ? xv0 : (j == 1) ? xv1 : (j == 2) ? xv2 : xv3;
            s0 += xv.x * w0[j].x + xv.y * w0[j].y + xv.z * w0[j].z + xv.w * w0[j].w;
            s1 += xv.x * w1[j].x + xv.y * w1[j].y + xv.z * w1[j].z + xv.w * w1[j].w;
            s2 += xv.x * w2[j].x + xv.y * w2[j].y + xv.z * w2[j].z + xv.w * w2[j].w;
        }
        // 64-lane butterfly reduction
        #pragma unroll
        for (int m = 32; m >= 1; m >>= 1) {
            s0 += __shfl_xor(s0, m);
            s1 += __shfl_xor(s1, m);
            s2 += __shfl_xor(s2, m);
        }
        if (lane == 0) {
            float* yr = y + (size_t)row * EDIM;   // [B, K, 3] row-major == reshape(B, 3K)
            yr[0] = s0;
            yr[1] = s1;
            yr[2] = s2;
        }
    }
}

// ---------------- Stage 1.5: transpose W_fc2 [OUT, 768] -> Wt [768, OUT] ----
__global__ __launch_bounds__(256) void transpose_wfc2(const float* __restrict__ W,
                                                      float* __restrict__ Wt) {
    int idx = blockIdx.x * 256 + threadIdx.x;   // index into Wt (coalesced write)
    if (idx < FC_IN * OUTN) {
        int j = idx >> 7;          // 0..767
        int o = idx & (OUTN - 1);  // 0..127
        Wt[idx] = W[o * FC_IN + j];
    }
}

// ---------------- Stage 2: out[b,o] = sum_j y[b,j] * Wt[j,o] + bias[o] ------
// 8 batch rows per block: Wt read once per block (64 blocks -> 25 MB L2 traffic)
__global__ __launch_bounds__(128) void stage2_fc(const float* __restrict__ y,
                                                 const float* __restrict__ Wt,
                                                 const float* __restrict__ bias,
                                                 float* __restrict__ out) {
    __shared__ float ys[S2_ROWS][FC_IN];   // 24 KB
    const int b0 = blockIdx.x * S2_ROWS;
    for (int i = threadIdx.x; i < S2_ROWS * FC_IN; i += 128) {
        ys[i / FC_IN][i % FC_IN] = y[(size_t)b0 * FC_IN + i];
    }
    __syncthreads();

    const int o = threadIdx.x;
    float acc[S2_ROWS];
    const float bo = bias[o];
    #pragma unroll
    for (int r = 0; r < S2_ROWS; ++r) acc[r] = bo;

    for (int j = 0; j < FC_IN; ++j) {
        const float w = Wt[j * OUTN + o];    // coalesced across lanes, L2-hit
        #pragma unroll
        for (int r = 0; r < S2_ROWS; ++r) acc[r] += ys[r][j] * w;  // broadcast LDS
    }
    #pragma unroll
    for (int r = 0; r < S2_ROWS; ++r) {
        out[(size_t)(b0 + r) * OUTN + o] = acc[r];
    }
}

extern "C" void kernel_launch(void* const* d_in, const int* in_sizes, int n_in,
                              void* d_out, int out_size, void* d_ws, size_t ws_size,
                              hipStream_t stream) {
    const float* x     = (const float*)d_in[0];   // [512, 256, 1000]
    const float* W_emb = (const float*)d_in[1];   // [3, 1000]
    const float* W_fc2 = (const float*)d_in[2];   // [128, 768]
    const float* b_fc2 = (const float*)d_in[3];   // [128]
    float* out = (float*)d_out;                   // [512, 128]

    // Workspace layout: y [131072*3] floats, then Wt [768*128] floats
    float* y  = (float*)d_ws;
    float* Wt = y + (size_t)NROWS * EDIM;

    // Stage 1: 2048 blocks x 256 threads (4 waves/block, grid-stride, 16 rows/wave)
    stage1_emb<<<2048, 256, 0, stream>>>(x, W_emb, y);

    // Transpose fc2 weight
    transpose_wfc2<<<(FC_IN * OUTN + 255) / 256, 256, 0, stream>>>(W_fc2, Wt);

    // Stage 2: 64 blocks, 8 batch rows each
    stage2_fc<<<BATCH / S2_ROWS, 128, 0, stream>>>(y, Wt, b_fc2, out);
}

// Round 3
// 147.214 us; speedup vs baseline: 1.0521x; 1.0521x over previous
//
#include <hip/hip_runtime.h>
#include <hip/hip_bf16.h>

// Problem constants (from reference)
#define BATCH 512
#define NKER  256
#define LEN   1000      // embedding input length
#define EDIM  3
#define OUTN  128
#define NROWS (BATCH * NKER)      // 131072
#define NF4   (LEN / 4)           // 250 float4 per row
#define FC_IN (EDIM * NKER)       // 768
#define ROWS_PER_WAVE 16          // 8192 waves x 16 rows = 131072

// ---------------- Stage 1: y[b,k,e] = sum_l x[b,k,l] * W_emb[e,l] ----------
// One wave per row-chunk of 16 consecutive rows. W_emb in LDS (keeps VGPR low).
// Fully unrolled 4-slice dot product; next row's loads issued before current
// row's compute (register double-buffer) so HBM loads stay in flight.
__global__ __launch_bounds__(256) void stage1_emb(const float* __restrict__ x,
                                                  const float* __restrict__ W_emb,
                                                  float* __restrict__ y) {
    __shared__ float w_s[EDIM][LEN];   // 12 KB
    for (int i = threadIdx.x; i < EDIM * LEN; i += 256) {
        w_s[i / LEN][i % LEN] = W_emb[i];
    }
    __syncthreads();

    const int wave = threadIdx.x >> 6;
    const int lane = threadIdx.x & 63;
    const int gw = blockIdx.x * 4 + wave;           // global wave id (8192 total)
    const int row0 = gw * ROWS_PER_WAVE;

    const bool tail = (lane < NF4 - 192);           // lane < 58 has a 4th slice
    const int f3 = tail ? (lane + 192) : 0;         // clamped LDS index (x is zeroed)
    const float4 z4 = make_float4(0.f, 0.f, 0.f, 0.f);

    const float4* w0p = reinterpret_cast<const float4*>(&w_s[0][0]);
    const float4* w1p = reinterpret_cast<const float4*>(&w_s[1][0]);
    const float4* w2p = reinterpret_cast<const float4*>(&w_s[2][0]);

    // Prime: load first row
    const float4* xr = reinterpret_cast<const float4*>(x + (size_t)row0 * LEN);
    float4 c0 = xr[lane];
    float4 c1 = xr[lane + 64];
    float4 c2 = xr[lane + 128];
    float4 c3 = tail ? xr[lane + 192] : z4;

    for (int i = 0; i < ROWS_PER_WAVE; ++i) {
        const int row = row0 + i;

        // Prefetch next row BEFORE using current row (loads in flight during compute)
        float4 n0, n1, n2, n3;
        if (i + 1 < ROWS_PER_WAVE) {     // uniform branch (scalar)
            const float4* xn = reinterpret_cast<const float4*>(x + (size_t)(row + 1) * LEN);
            n0 = xn[lane];
            n1 = xn[lane + 64];
            n2 = xn[lane + 128];
            n3 = tail ? xn[lane + 192] : z4;
        } else {
            n0 = n1 = n2 = n3 = z4;
        }

        // Fully unrolled dot products (LDS W reads, short-lived temps)
        float s0, s1, s2;
        {
            float4 w;
            w = w0p[lane];        s0  = c0.x*w.x + c0.y*w.y + c0.z*w.z + c0.w*w.w;
            w = w0p[lane + 64];   s0 += c1.x*w.x + c1.y*w.y + c1.z*w.z + c1.w*w.w;
            w = w0p[lane + 128];  s0 += c2.x*w.x + c2.y*w.y + c2.z*w.z + c2.w*w.w;
            w = w0p[f3];          s0 += c3.x*w.x + c3.y*w.y + c3.z*w.z + c3.w*w.w;

            w = w1p[lane];        s1  = c0.x*w.x + c0.y*w.y + c0.z*w.z + c0.w*w.w;
            w = w1p[lane + 64];   s1 += c1.x*w.x + c1.y*w.y + c1.z*w.z + c1.w*w.w;
            w = w1p[lane + 128];  s1 += c2.x*w.x + c2.y*w.y + c2.z*w.z + c2.w*w.w;
            w = w1p[f3];          s1 += c3.x*w.x + c3.y*w.y + c3.z*w.z + c3.w*w.w;

            w = w2p[lane];        s2  = c0.x*w.x + c0.y*w.y + c0.z*w.z + c0.w*w.w;
            w = w2p[lane + 64];   s2 += c1.x*w.x + c1.y*w.y + c1.z*w.z + c1.w*w.w;
            w = w2p[lane + 128];  s2 += c2.x*w.x + c2.y*w.y + c2.z*w.z + c2.w*w.w;
            w = w2p[f3];          s2 += c3.x*w.x + c3.y*w.y + c3.z*w.z + c3.w*w.w;
        }

        // 64-lane butterfly reduction
        #pragma unroll
        for (int m = 32; m >= 1; m >>= 1) {
            s0 += __shfl_xor(s0, m);
            s1 += __shfl_xor(s1, m);
            s2 += __shfl_xor(s2, m);
        }
        if (lane == 0) {
            float* yr = y + (size_t)row * EDIM;   // [B, K, 3] row-major == reshape(B, 3K)
            yr[0] = s0;
            yr[1] = s1;
            yr[2] = s2;
        }

        c0 = n0; c1 = n1; c2 = n2; c3 = n3;
    }
}

// ---------------- Stage 1.5: transpose W_fc2 [OUT, 768] -> Wt [768, OUT] ----
__global__ __launch_bounds__(256) void transpose_wfc2(const float* __restrict__ W,
                                                      float* __restrict__ Wt) {
    int idx = blockIdx.x * 256 + threadIdx.x;   // index into Wt (coalesced write)
    if (idx < FC_IN * OUTN) {
        int j = idx >> 7;          // 0..767
        int o = idx & (OUTN - 1);  // 0..127
        Wt[idx] = W[o * FC_IN + j];
    }
}

// ---------------- Stage 2: out[b,o] = sum_j y[b,j] * Wt[j,o] + bias[o] ------
// Round-0 proven version: one block per batch row.
__global__ __launch_bounds__(128) void stage2_fc(const float* __restrict__ y,
                                                 const float* __restrict__ Wt,
                                                 const float* __restrict__ bias,
                                                 float* __restrict__ out) {
    __shared__ float ys[FC_IN];
    const int b = blockIdx.x;
    for (int i = threadIdx.x; i < FC_IN; i += 128) ys[i] = y[(size_t)b * FC_IN + i];
    __syncthreads();

    const int o = threadIdx.x;
    float acc = bias[o];
    #pragma unroll 8
    for (int j = 0; j < FC_IN; ++j) {
        acc += ys[j] * Wt[j * OUTN + o];   // ys[j] broadcast; Wt coalesced across lanes
    }
    out[(size_t)b * OUTN + o] = acc;
}

extern "C" void kernel_launch(void* const* d_in, const int* in_sizes, int n_in,
                              void* d_out, int out_size, void* d_ws, size_t ws_size,
                              hipStream_t stream) {
    const float* x     = (const float*)d_in[0];   // [512, 256, 1000]
    const float* W_emb = (const float*)d_in[1];   // [3, 1000]
    const float* W_fc2 = (const float*)d_in[2];   // [128, 768]
    const float* b_fc2 = (const float*)d_in[3];   // [128]
    float* out = (float*)d_out;                   // [512, 128]

    // Workspace layout: y [131072*3] floats, then Wt [768*128] floats
    float* y  = (float*)d_ws;
    float* Wt = y + (size_t)NROWS * EDIM;

    // Stage 1: 2048 blocks x 256 threads; each wave streams 16 consecutive rows
    stage1_emb<<<2048, 256, 0, stream>>>(x, W_emb, y);

    // Transpose fc2 weight
    transpose_wfc2<<<(FC_IN * OUTN + 255) / 256, 256, 0, stream>>>(W_fc2, Wt);

    // Stage 2: one block per batch row
    stage2_fc<<<BATCH, 128, 0, stream>>>(y, Wt, b_fc2, out);
}

// Round 4
// 118.474 us; speedup vs baseline: 1.3073x; 1.2426x over previous
//
#include <hip/hip_runtime.h>
#include <hip/hip_bf16.h>

// Problem constants (from reference)
#define BATCH 512
#define NKER  256
#define LEN   1000      // embedding input length
#define EDIM  3
#define OUTN  128
#define NROWS (BATCH * NKER)      // 131072
#define NF4   (LEN / 4)           // 250 float4 per row
#define FC_IN (EDIM * NKER)       // 768

#define DOT4(a, w) ((a).x*(w).x + (a).y*(w).y + (a).z*(w).z + (a).w*(w).w)

// ---------------- Stage 1: y[b,k,e] = sum_l x[b,k,l] * W_emb[e,l] ----------
// One wave per PAIR of consecutive rows per iteration (8 pairs/wave, strided).
// W_emb in LDS; each W float4 is read once per pair and used for both rows
// (halves W LDS traffic vs round 0). All 8 x loads issued up front (~32 VGPR
// of load buffer; total stays under the 64-VGPR occupancy step).
__global__ __launch_bounds__(256) void stage1_emb(const float* __restrict__ x,
                                                  const float* __restrict__ W_emb,
                                                  float* __restrict__ y) {
    __shared__ float w_s[EDIM][LEN];   // 12 KB
    for (int i = threadIdx.x; i < EDIM * LEN; i += 256) {
        w_s[i / LEN][i % LEN] = W_emb[i];
    }
    __syncthreads();

    const int wave = threadIdx.x >> 6;
    const int lane = threadIdx.x & 63;
    const int gw = blockIdx.x * 4 + wave;           // global wave id, 0..8191

    const bool tail = (lane < NF4 - 192);           // lane < 58 has a 4th slice
    const int f3 = tail ? (lane + 192) : 0;         // clamped LDS index (x zeroed)
    const float4 z4 = make_float4(0.f, 0.f, 0.f, 0.f);

    const float4* w0p = reinterpret_cast<const float4*>(&w_s[0][0]);
    const float4* w1p = reinterpret_cast<const float4*>(&w_s[1][0]);
    const float4* w2p = reinterpret_cast<const float4*>(&w_s[2][0]);

    #pragma unroll 1
    for (int i = 0; i < 8; ++i) {
        const int rowA = gw * 2 + i * 16384;        // pairs strided across array
        const float4* xa = reinterpret_cast<const float4*>(x + (size_t)rowA * LEN);
        const float4* xb = reinterpret_cast<const float4*>(x + (size_t)(rowA + 1) * LEN);

        // Issue all 8 loads before any use (8 KB contiguous in flight per wave)
        float4 a0 = xa[lane];
        float4 a1 = xa[lane + 64];
        float4 a2 = xa[lane + 128];
        float4 a3 = tail ? xa[lane + 192] : z4;
        float4 b0 = xb[lane];
        float4 b1 = xb[lane + 64];
        float4 b2 = xb[lane + 128];
        float4 b3 = tail ? xb[lane + 192] : z4;

        float sA0, sA1, sA2, sB0, sB1, sB2;
        {
            float4 w;
            // chunk 0 (W read once, used for both rows)
            w = w0p[lane];       sA0  = DOT4(a0, w);  sB0  = DOT4(b0, w);
            w = w1p[lane];       sA1  = DOT4(a0, w);  sB1  = DOT4(b0, w);
            w = w2p[lane];       sA2  = DOT4(a0, w);  sB2  = DOT4(b0, w);
            // chunk 1
            w = w0p[lane + 64];  sA0 += DOT4(a1, w);  sB0 += DOT4(b1, w);
            w = w1p[lane + 64];  sA1 += DOT4(a1, w);  sB1 += DOT4(b1, w);
            w = w2p[lane + 64];  sA2 += DOT4(a1, w);  sB2 += DOT4(b1, w);
            // chunk 2
            w = w0p[lane + 128]; sA0 += DOT4(a2, w);  sB0 += DOT4(b2, w);
            w = w1p[lane + 128]; sA1 += DOT4(a2, w);  sB1 += DOT4(b2, w);
            w = w2p[lane + 128]; sA2 += DOT4(a2, w);  sB2 += DOT4(b2, w);
            // chunk 3 (tail; x zeroed for lanes >= 58, W index clamped)
            w = w0p[f3];         sA0 += DOT4(a3, w);  sB0 += DOT4(b3, w);
            w = w1p[f3];         sA1 += DOT4(a3, w);  sB1 += DOT4(b3, w);
            w = w2p[f3];         sA2 += DOT4(a3, w);  sB2 += DOT4(b3, w);
        }

        // 64-lane butterfly reduction (6 values per pair)
        #pragma unroll
        for (int m = 32; m >= 1; m >>= 1) {
            sA0 += __shfl_xor(sA0, m);
            sA1 += __shfl_xor(sA1, m);
            sA2 += __shfl_xor(sA2, m);
            sB0 += __shfl_xor(sB0, m);
            sB1 += __shfl_xor(sB1, m);
            sB2 += __shfl_xor(sB2, m);
        }
        if (lane == 0) {
            float* yr = y + (size_t)rowA * EDIM;   // rows A,B contiguous: 24 B
            yr[0] = sA0;
            yr[1] = sA1;
            yr[2] = sA2;
            yr[3] = sB0;
            yr[4] = sB1;
            yr[5] = sB2;
        }
    }
}

// ---------------- Stage 1.5: transpose W_fc2 [OUT, 768] -> Wt [768, OUT] ----
__global__ __launch_bounds__(256) void transpose_wfc2(const float* __restrict__ W,
                                                      float* __restrict__ Wt) {
    int idx = blockIdx.x * 256 + threadIdx.x;   // index into Wt (coalesced write)
    if (idx < FC_IN * OUTN) {
        int j = idx >> 7;          // 0..767
        int o = idx & (OUTN - 1);  // 0..127
        Wt[idx] = W[o * FC_IN + j];
    }
}

// ---------------- Stage 2: out[b,o] = sum_j y[b,j] * Wt[j,o] + bias[o] ------
// 256 threads/block: thread = (o, j-half). Doubles waves/SIMD vs round 0 and
// halves the serial j-chain per thread; LDS-combine the two halves.
__global__ __launch_bounds__(256) void stage2_fc(const float* __restrict__ y,
                                                 const float* __restrict__ Wt,
                                                 const float* __restrict__ bias,
                                                 float* __restrict__ out) {
    __shared__ float ys[FC_IN];
    __shared__ float part[OUTN];
    const int b = blockIdx.x;
    for (int i = threadIdx.x; i < FC_IN; i += 256) ys[i] = y[(size_t)b * FC_IN + i];
    __syncthreads();

    const int o = threadIdx.x & (OUTN - 1);
    const int h = threadIdx.x >> 7;               // 0 or 1
    const int j0 = h * (FC_IN / 2);
    float acc = 0.f;
    #pragma unroll 8
    for (int j = j0; j < j0 + FC_IN / 2; ++j) {
        acc += ys[j] * Wt[j * OUTN + o];   // ys[j] broadcast; Wt coalesced across lanes
    }
    if (h) part[o] = acc;
    __syncthreads();
    if (!h) out[(size_t)b * OUTN + o] = acc + part[o] + bias[o];
}

extern "C" void kernel_launch(void* const* d_in, const int* in_sizes, int n_in,
                              void* d_out, int out_size, void* d_ws, size_t ws_size,
                              hipStream_t stream) {
    const float* x     = (const float*)d_in[0];   // [512, 256, 1000]
    const float* W_emb = (const float*)d_in[1];   // [3, 1000]
    const float* W_fc2 = (const float*)d_in[2];   // [128, 768]
    const float* b_fc2 = (const float*)d_in[3];   // [128]
    float* out = (float*)d_out;                   // [512, 128]

    // Workspace layout: y [131072*3] floats, then Wt [768*128] floats
    float* y  = (float*)d_ws;
    float* Wt = y + (size_t)NROWS * EDIM;

    // Stage 1: 2048 blocks x 256 threads; each wave does 8 strided row-pairs
    stage1_emb<<<2048, 256, 0, stream>>>(x, W_emb, y);

    // Transpose fc2 weight
    transpose_wfc2<<<(FC_IN * OUTN + 255) / 256, 256, 0, stream>>>(W_fc2, Wt);

    // Stage 2: one block per batch row, 256 threads (o x j-half)
    stage2_fc<<<BATCH, 256, 0, stream>>>(y, Wt, b_fc2, out);
}